// Round 10
// baseline (406.029 us; speedup 1.0000x reference)
//
#include <hip/hip_runtime.h>
#include <hip/hip_bf16.h>
#include <math.h>

// Problem constants (fixed by reference)
constexpr int BB = 4;
constexpr int LL = 2048;
constexpr int EE = 512;
constexpr int HH = 8;
constexpr int DD = 64;
constexpr int UU = 40;    // sample count
constexpr int NT = 40;    // n_top
constexpr int NCH = 32;   // key chunks (64 keys each) for split-K attention
constexpr int CK = 64;    // keys per chunk
constexpr int MVC = 16;   // L-chunks for meanv stage 1 (128 rows each)
constexpr float NEG_INF = -3.0e38f;

typedef __attribute__((ext_vector_type(8))) short bf8_t;  // 8 bf16 (4 VGPR)
typedef __attribute__((ext_vector_type(4))) float f4_t;   // MFMA C/D frag

// ---------------------------------------------------------------------------
// K1: fused QKV projection via split-bf16 MFMA, 3-product, software-pipelined.
// f32 = hi(RNE bf16) + mid(trunc bf16) + eps; products hh+hm+mh.
// Pipeline: regs(kt) -> barrier -> LDS write -> barrier -> load+split(kt+1)
// -> MFMA(kt): the prefetch issues under the MFMA block (independent of LDS
// reads), hiding global latency + split VALU.
// Tile 128x128x32, 4 waves (2x2 of 64x64), 16x16x32 bf16 MFMA. LDS 32 KB.
// ---------------------------------------------------------------------------
__device__ __forceinline__ void split2(float x, uint& h, uint& m)
{
    uint  xb = __float_as_uint(x);
    uint  hb = (xb + 0x7fffu + ((xb >> 16) & 1u)) & 0xffff0000u;  // RNE bf16
    float r  = x - __uint_as_float(hb);
    h = hb >> 16;
    m = (__float_as_uint(r) & 0xffff0000u) >> 16;                 // trunc
}

__device__ __forceinline__ int swz(int row, int c)
{
    return row * 64 + (((c ^ row ^ (row >> 2)) & 3) << 4);
}

__global__ __launch_bounds__(256, 4) void proj_kernel(
    const float* __restrict__ Xq, const float* __restrict__ Xk, const float* __restrict__ Xv,
    const float* __restrict__ Wq, const float* __restrict__ Wk, const float* __restrict__ Wv,
    const float* __restrict__ bq, const float* __restrict__ bk, const float* __restrict__ bv,
    float* __restrict__ Oq, float* __restrict__ Ok, float* __restrict__ Ov)
{
    const float* X; const float* W; const float* bias; float* O;
    if (blockIdx.z == 0)      { X = Xq; W = Wq; bias = bq; O = Oq; }
    else if (blockIdx.z == 1) { X = Xk; W = Wk; bias = bk; O = Ok; }
    else                      { X = Xv; W = Wv; bias = bv; O = Ov; }

    __shared__ char ldsmem[32768];   // A: hi@0 mid@8192; B: hi@0 mid@8192 (in LB)
    char* const LA = ldsmem;
    char* const LB = ldsmem + 16384;

    const int tid  = threadIdx.x;
    const int lane = tid & 63;
    const int wave = tid >> 6;
    const int m0 = blockIdx.y * 128;
    const int n0 = blockIdx.x * 128;

    const int srow  = tid >> 1;
    const int shalf = tid & 1;
    const int w0 = swz(srow, shalf * 2);
    const int w1 = swz(srow, shalf * 2 + 1);
    const float* Aptr = X + (size_t)(m0 + srow) * EE + shalf * 16;
    const float* Bptr = W + (size_t)(n0 + srow) * EE + shalf * 16;

    const int rxor = ((((lane >> 4) ^ lane ^ (lane >> 2)) & 3) << 4);
    const int arow = (wave >> 1) * 64 + (lane & 15);
    const int brow = (wave & 1) * 64 + (lane & 15);

    f4_t acc[4][4];
#pragma unroll
    for (int i = 0; i < 4; i++)
#pragma unroll
        for (int j = 0; j < 4; j++) acc[i][j] = (f4_t)0.0f;

    uint ahu[8], amu[8], bhu[8], bmu[8];

    auto load_split = [&](int kt) {
        float fa[16], fb[16];
#pragma unroll
        for (int q = 0; q < 4; q++) {
            *(float4*)(fa + q * 4) = *(const float4*)(Aptr + kt + q * 4);
            *(float4*)(fb + q * 4) = *(const float4*)(Bptr + kt + q * 4);
        }
#pragma unroll
        for (int p = 0; p < 8; p++) {
            uint h0, m0_, h1, m1_;
            split2(fa[2 * p], h0, m0_);
            split2(fa[2 * p + 1], h1, m1_);
            ahu[p] = h0 | (h1 << 16); amu[p] = m0_ | (m1_ << 16);
            split2(fb[2 * p], h0, m0_);
            split2(fb[2 * p + 1], h1, m1_);
            bhu[p] = h0 | (h1 << 16); bmu[p] = m0_ | (m1_ << 16);
        }
    };

    load_split(0);

    for (int kt = 0; kt < EE; kt += 32) {
        __syncthreads();   // previous tile's readers done
        *(uint4*)(LA +     0 + w0) = make_uint4(ahu[0], ahu[1], ahu[2], ahu[3]);
        *(uint4*)(LA +     0 + w1) = make_uint4(ahu[4], ahu[5], ahu[6], ahu[7]);
        *(uint4*)(LA +  8192 + w0) = make_uint4(amu[0], amu[1], amu[2], amu[3]);
        *(uint4*)(LA +  8192 + w1) = make_uint4(amu[4], amu[5], amu[6], amu[7]);
        *(uint4*)(LB +     0 + w0) = make_uint4(bhu[0], bhu[1], bhu[2], bhu[3]);
        *(uint4*)(LB +     0 + w1) = make_uint4(bhu[4], bhu[5], bhu[6], bhu[7]);
        *(uint4*)(LB +  8192 + w0) = make_uint4(bmu[0], bmu[1], bmu[2], bmu[3]);
        *(uint4*)(LB +  8192 + w1) = make_uint4(bmu[4], bmu[5], bmu[6], bmu[7]);
        __syncthreads();   // tile ready

        // prefetch + split next tile; independent of the LDS reads below, so
        // the scheduler issues these loads/VALU under the MFMA block.
        if (kt + 32 < EE) load_split(kt + 32);

        bf8_t af[4][2];
#pragma unroll
        for (int i = 0; i < 4; i++) {
            const int ro = (arow + i * 16) * 64 + rxor;
            af[i][0] = *(const bf8_t*)(LA +    0 + ro);
            af[i][1] = *(const bf8_t*)(LA + 8192 + ro);
        }
#pragma unroll
        for (int j = 0; j < 4; j++) {
            const int ro = (brow + j * 16) * 64 + rxor;
            bf8_t bh_ = *(const bf8_t*)(LB +    0 + ro);
            bf8_t bm_ = *(const bf8_t*)(LB + 8192 + ro);
#pragma unroll
            for (int i = 0; i < 4; i++) {
                f4_t c = acc[i][j];
                c = __builtin_amdgcn_mfma_f32_16x16x32_bf16(af[i][0], bh_, c, 0, 0, 0); // hh
                c = __builtin_amdgcn_mfma_f32_16x16x32_bf16(af[i][0], bm_, c, 0, 0, 0); // hm
                c = __builtin_amdgcn_mfma_f32_16x16x32_bf16(af[i][1], bh_, c, 0, 0, 0); // mh
                acc[i][j] = c;
            }
        }
    }

#pragma unroll
    for (int j = 0; j < 4; j++) {
        const int n  = n0 + (wave & 1) * 64 + j * 16 + (lane & 15);
        const float bn = bias[n];
        const int h_ = n >> 6, d_ = n & 63;
#pragma unroll
        for (int i = 0; i < 4; i++) {
            const int mb = m0 + (wave >> 1) * 64 + i * 16 + ((lane >> 4) << 2);
#pragma unroll
            for (int r = 0; r < 4; r++) {
                const int m  = mb + r;
                const int b_ = m >> 11;
                const int l_ = m & (LL - 1);
                O[(((size_t)(b_ * HH + h_) * LL + l_) << 6) + d_] = acc[i][j][r] + bn;
            }
        }
    }
}

// ---------------------------------------------------------------------------
// K2a: mean of V stage 1 — 512 blocks = (lchunk 0..15) x (bh 0..31).
// ---------------------------------------------------------------------------
__global__ __launch_bounds__(256) void meanv_part_kernel(const float* __restrict__ v,
                                                         float* __restrict__ vpart)
{
    const int bh    = blockIdx.x & 31;
    const int chunk = blockIdx.x >> 5;
    const int d  = threadIdx.x & 63;
    const int wv = threadIdx.x >> 6;
    const float* base = v + ((size_t)bh * LL + chunk * 128 + wv * 32) * DD + d;
    float acc = 0.0f;
#pragma unroll
    for (int i = 0; i < 32; i++) acc += base[i * DD];
    __shared__ float red[4][DD];
    red[wv][d] = acc;
    __syncthreads();
    if (wv == 0)
        vpart[(size_t)(chunk * 32 + bh) * DD + d]
            = red[0][d] + red[1][d] + red[2][d] + red[3][d];
}

// ---------------------------------------------------------------------------
// K2b: mean of V stage 2 — combine 16 partials per (bh,d).
// ---------------------------------------------------------------------------
__global__ __launch_bounds__(64) void meanv_comb_kernel(const float* __restrict__ vpart,
                                                        float* __restrict__ mean_v)
{
    const int bh = blockIdx.x;
    const int d  = threadIdx.x;
    float s = 0.0f;
#pragma unroll
    for (int c = 0; c < MVC; c++) s += vpart[(size_t)(c * 32 + bh) * DD + d];
    mean_v[bh * DD + d] = s * (1.0f / (float)LL);
}

// ---------------------------------------------------------------------------
// K3: sparsity measure M[b,h,l] = max_s(q.k_sample) - sum_s(q.k_sample)/L
// One wave per (b,h,l). Lane map: 8 samples x 8 d-chunks. XCD-swizzled grid.
// ---------------------------------------------------------------------------
__global__ __launch_bounds__(256) void measure_kernel(const float* __restrict__ q,
                                                      const float* __restrict__ k,
                                                      const int* __restrict__ idx_sample,
                                                      float* __restrict__ M)
{
    int bh   = blockIdx.x & 31;
    int lc   = blockIdx.x >> 5;
    int lane = threadIdx.x & 63;
    int wv   = threadIdx.x >> 6;
    int l    = lc * 4 + wv;
    int s8   = lane >> 3;   // sample slot 0..7
    int c    = lane & 7;    // d-chunk 0..7

    const float* qrow = q + ((size_t)bh * LL + l) * DD + c * 8;
    float4 q0 = *(const float4*)(qrow);
    float4 q1 = *(const float4*)(qrow + 4);

    const float* kbase = k + (size_t)bh * LL * DD;
    const int*   irow  = idx_sample + l * UU;

    float mx = NEG_INF, sum = 0.0f;
#pragma unroll
    for (int it = 0; it < UU; it += 8) {
        int ki = irow[it + s8];
        const float* krow = kbase + (size_t)ki * DD + c * 8;
        float4 k0 = *(const float4*)(krow);
        float4 k1 = *(const float4*)(krow + 4);
        float p = q0.x*k0.x + q0.y*k0.y + q0.z*k0.z + q0.w*k0.w
                + q1.x*k1.x + q1.y*k1.y + q1.z*k1.z + q1.w*k1.w;
        p += __shfl_xor(p, 1, 64);
        p += __shfl_xor(p, 2, 64);
        p += __shfl_xor(p, 4, 64);
        mx = fmaxf(mx, p);
        sum += p;
    }
    mx  = fmaxf(mx, __shfl_xor(mx, 8, 64));
    sum += __shfl_xor(sum, 8, 64);
    mx  = fmaxf(mx, __shfl_xor(mx, 16, 64));
    sum += __shfl_xor(sum, 16, 64);
    mx  = fmaxf(mx, __shfl_xor(mx, 32, 64));
    sum += __shfl_xor(sum, 32, 64);

    if (lane == 0) M[bh * LL + l] = mx - sum * (1.0f / (float)LL);
}

// ---------------------------------------------------------------------------
// K4: top-40 per (b,h), single-wave register version.
// ---------------------------------------------------------------------------
__global__ __launch_bounds__(64) void topk_kernel(const float* __restrict__ M,
                                                  int* __restrict__ top)
{
    const int bh   = blockIdx.x;
    const int lane = threadIdx.x;

    unsigned long long keys[32];
#pragma unroll
    for (int i = 0; i < 32; i++) {
        int idx = i * 64 + lane;
        uint u  = __float_as_uint(M[bh * LL + idx]);
        uint sv = (u & 0x80000000u) ? ~u : (u | 0x80000000u);
        keys[i] = ((unsigned long long)sv << 32) | (uint)(LL - 1 - idx);
    }
    unsigned long long lmax = 0ull;
#pragma unroll
    for (int i = 0; i < 32; i++) lmax = (keys[i] > lmax) ? keys[i] : lmax;

    for (int it = 0; it < NT; it++) {
        unsigned long long g = lmax;
#pragma unroll
        for (int off = 1; off < 64; off <<= 1) {
            unsigned long long o = __shfl_xor(g, off, 64);
            g = (o > g) ? o : g;
        }
        if (lane == 0) top[bh * NT + it] = LL - 1 - (int)(g & 0xffffffffu);
#pragma unroll
        for (int i = 0; i < 32; i++) if (keys[i] == g) keys[i] = 0ull;
        lmax = 0ull;
#pragma unroll
        for (int i = 0; i < 32; i++) lmax = (keys[i] > lmax) ? keys[i] : lmax;
    }
}

// ---------------------------------------------------------------------------
// K5: flash-style split-K attention partials.
// ---------------------------------------------------------------------------
__global__ __launch_bounds__(256) void pv_kernel(const float* __restrict__ q,
                                                 const float* __restrict__ k,
                                                 const float* __restrict__ v,
                                                 const int* __restrict__ top,
                                                 float* __restrict__ mpart,
                                                 float* __restrict__ lpart,
                                                 float* __restrict__ accpart)
{
    const int bh    = blockIdx.x & 31;
    const int chunk = blockIdx.x >> 5;
    const int tid   = threadIdx.x;
    const int lane  = tid & 63, wv = tid >> 6;

    __shared__ float qs[NT][DD];        // 10240 B
    __shared__ float sc[NT][CK + 4];    // 10880 B

    for (int i = tid; i < NT * DD / 4; i += 256) {
        int u  = i >> 4;
        int d4 = (i & 15) * 4;
        int l  = top[bh * NT + u];
        *(float4*)&qs[u][d4] = *(const float4*)(q + ((size_t)bh * LL + l) * DD + d4);
    }
    __syncthreads();

    {
        const int key  = tid >> 2;
        const int dseg = tid & 3;
        const float* krow = k + ((size_t)bh * LL + chunk * CK + key) * DD + dseg * 16;
        float4 k0 = *(const float4*)(krow);
        float4 k1 = *(const float4*)(krow + 4);
        float4 k2 = *(const float4*)(krow + 8);
        float4 k3 = *(const float4*)(krow + 12);
#pragma unroll 8
        for (int u = 0; u < NT; u++) {
            const float* qrow = &qs[u][dseg * 16];
            float4 q0 = *(const float4*)(qrow);
            float4 q1 = *(const float4*)(qrow + 4);
            float4 q2 = *(const float4*)(qrow + 8);
            float4 q3 = *(const float4*)(qrow + 12);
            float p = k0.x*q0.x + k0.y*q0.y + k0.z*q0.z + k0.w*q0.w
                    + k1.x*q1.x + k1.y*q1.y + k1.z*q1.z + k1.w*q1.w
                    + k2.x*q2.x + k2.y*q2.y + k2.z*q2.z + k2.w*q2.w
                    + k3.x*q3.x + k3.y*q3.y + k3.z*q3.z + k3.w*q3.w;
            p += __shfl_xor(p, 1, 64);
            p += __shfl_xor(p, 2, 64);
            if (dseg == 0) sc[u][key] = p;
        }
    }
    __syncthreads();

#pragma unroll
    for (int i = 0; i < 10; i++) {
        const int u = wv * 10 + i;
        float val = sc[u][lane];
        float mx = val;
        mx = fmaxf(mx, __shfl_xor(mx, 1, 64));
        mx = fmaxf(mx, __shfl_xor(mx, 2, 64));
        mx = fmaxf(mx, __shfl_xor(mx, 4, 64));
        mx = fmaxf(mx, __shfl_xor(mx, 8, 64));
        mx = fmaxf(mx, __shfl_xor(mx, 16, 64));
        mx = fmaxf(mx, __shfl_xor(mx, 32, 64));
        float e = __expf(val - mx);
        sc[u][lane] = e;
        float s = e;
        s += __shfl_xor(s, 1, 64);
        s += __shfl_xor(s, 2, 64);
        s += __shfl_xor(s, 4, 64);
        s += __shfl_xor(s, 8, 64);
        s += __shfl_xor(s, 16, 64);
        s += __shfl_xor(s, 32, 64);
        if (lane == 0) {
            mpart[(bh * NCH + chunk) * NT + u] = mx;
            lpart[(bh * NCH + chunk) * NT + u] = s;
        }
    }
    __syncthreads();

    {
        float pacc[10];
#pragma unroll
        for (int i = 0; i < 10; i++) pacc[i] = 0.0f;
        const float* vbase = v + ((size_t)bh * LL + chunk * CK) * DD;
#pragma unroll 8
        for (int t = 0; t < CK; t++) {
            float vval = vbase[(size_t)t * DD + lane];
#pragma unroll
            for (int i = 0; i < 10; i++) pacc[i] += sc[wv * 10 + i][t] * vval;
        }
#pragma unroll
        for (int i = 0; i < 10; i++) {
            const int u = wv * 10 + i;
            accpart[(((size_t)(bh * NCH + chunk)) * NT + u) * 64 + lane] = pacc[i];
        }
    }
}

// ---------------------------------------------------------------------------
// K6a: base output row per batch: base[b,e] = meanctx[b,:] . Wo[e,:] + bo[e]
// ---------------------------------------------------------------------------
__global__ __launch_bounds__(256) void base_kernel(const float* __restrict__ mean_v,
                                                   const float* __restrict__ Wo,
                                                   const float* __restrict__ bo,
                                                   float* __restrict__ base)
{
    int lane = threadIdx.x & 63, wv = threadIdx.x >> 6;
    int be = blockIdx.x * 4 + wv;
    int b  = be >> 9;
    int e  = be & (EE - 1);
    const float* mrow = mean_v + b * EE;
    const float* wrow = Wo + (size_t)e * EE;
    float acc = 0.0f;
#pragma unroll
    for (int j = 0; j < 8; j++) acc += mrow[lane + j * 64] * wrow[lane + j * 64];
#pragma unroll
    for (int off = 32; off > 0; off >>= 1) acc += __shfl_down(acc, off, 64);
    if (lane == 0) base[be] = acc + bo[e];
}

// ---------------------------------------------------------------------------
// K6b: broadcast base row to all l
// ---------------------------------------------------------------------------
__global__ __launch_bounds__(256) void bcast_kernel(const float* __restrict__ base,
                                                    float* __restrict__ out)
{
    size_t fi = ((size_t)blockIdx.x * 256 + threadIdx.x) * 4;
    int b  = (int)(fi >> 20);
    int e4 = (int)(fi & (EE - 1));
    float4 val = *(const float4*)(base + b * EE + e4);
    *(float4*)(out + fi) = val;
}

// ---------------------------------------------------------------------------
// K6c: combine chunk partials (online-softmax merge) + correction GEMV.
// ---------------------------------------------------------------------------
__global__ __launch_bounds__(256) void corr_kernel(const float* __restrict__ accpart,
                                                   const float* __restrict__ lpart,
                                                   const float* __restrict__ mpart,
                                                   const float* __restrict__ mean_v,
                                                   const int* __restrict__ top,
                                                   const float* __restrict__ Wo,
                                                   float* __restrict__ out)
{
    int bhu = blockIdx.x;
    int bh  = bhu / NT;
    int u   = bhu % NT;
    int h   = bh & (HH - 1);
    int b   = bh >> 3;
    int tid = threadIdx.x;
    int l   = top[bhu];

    __shared__ float delta[DD];
    if (tid < DD) {
        float m = NEG_INF;
#pragma unroll 8
        for (int c = 0; c < NCH; c++) m = fmaxf(m, mpart[(bh * NCH + c) * NT + u]);
        float den = 0.0f, num = 0.0f;
#pragma unroll 8
        for (int c = 0; c < NCH; c++) {
            float f = __expf(mpart[(bh * NCH + c) * NT + u] - m);
            den += lpart[(bh * NCH + c) * NT + u] * f;
            num += accpart[(((size_t)(bh * NCH + c)) * NT + u) * 64 + tid] * f;
        }
        delta[tid] = num / den - mean_v[bh * DD + tid];
    }
    __syncthreads();

    float* orow = out + ((size_t)(b * LL + l)) * EE;
#pragma unroll
    for (int rep = 0; rep < 2; rep++) {
        int e = tid + rep * 256;
        const float* wrow = Wo + (size_t)e * EE + h * DD;
        float acc = 0.0f;
#pragma unroll
        for (int d = 0; d < DD; d++) acc += delta[d] * wrow[d];
        atomicAdd(orow + e, acc);
    }
}

// ---------------------------------------------------------------------------
extern "C" void kernel_launch(void* const* d_in, const int* in_sizes, int n_in,
                              void* d_out, int out_size, void* d_ws, size_t ws_size,
                              hipStream_t stream)
{
    const float* query = (const float*)d_in[0];
    const float* key   = (const float*)d_in[1];
    const float* value = (const float*)d_in[2];
    const int*   idxs  = (const int*)d_in[3];
    const float* Wq = (const float*)d_in[4];
    const float* bq = (const float*)d_in[5];
    const float* Wk = (const float*)d_in[6];
    const float* bk = (const float*)d_in[7];
    const float* Wv = (const float*)d_in[8];
    const float* bv = (const float*)d_in[9];
    const float* Wo = (const float*)d_in[10];
    const float* bo = (const float*)d_in[11];
    float* out = (float*)d_out;

    // workspace layout (~62 MB)
    char* ws = (char*)d_ws;
    size_t off = 0;
    const size_t qkv_bytes = (size_t)BB * HH * LL * DD * sizeof(float); // 16 MB each
    float* q_ws = (float*)(ws + off); off += qkv_bytes;
    float* k_ws = (float*)(ws + off); off += qkv_bytes;
    float* v_ws = (float*)(ws + off); off += qkv_bytes;
    float* M_ws    = (float*)(ws + off); off += (size_t)BB * HH * LL * sizeof(float);
    int*   top_ws  = (int*)(ws + off);   off += (size_t)BB * HH * NT * sizeof(int);
    float* mean_ws = (float*)(ws + off); off += (size_t)BB * HH * DD * sizeof(float);
    float* vpart_ws = (float*)(ws + off); off += (size_t)BB * HH * MVC * DD * sizeof(float);
    float* mpart_ws = (float*)(ws + off); off += (size_t)BB * HH * NCH * NT * sizeof(float);
    float* lpart_ws = (float*)(ws + off); off += (size_t)BB * HH * NCH * NT * sizeof(float);
    float* accpart_ws = (float*)(ws + off); off += (size_t)BB * HH * NCH * NT * DD * sizeof(float);
    float* base_ws = (float*)(ws + off); off += (size_t)BB * EE * sizeof(float);

    // K1: QKV projections (split-bf16 MFMA, 3 products, pipelined)
    dim3 g1(EE / 128, (BB * LL) / 128, 3);
    proj_kernel<<<g1, 256, 0, stream>>>(query, key, value, Wq, Wk, Wv, bq, bk, bv,
                                        q_ws, k_ws, v_ws);
    // K2: mean of V (two-stage)
    meanv_part_kernel<<<BB * HH * MVC, 256, 0, stream>>>(v_ws, vpart_ws);
    meanv_comb_kernel<<<BB * HH, 64, 0, stream>>>(vpart_ws, mean_ws);
    // K3: sparsity measure (XCD-swizzled grid)
    measure_kernel<<<(LL / 4) * 32, 256, 0, stream>>>(q_ws, k_ws, idxs, M_ws);
    // K4: top-40 (single wave per bh)
    topk_kernel<<<BB * HH, 64, 0, stream>>>(M_ws, top_ws);
    // K5: split-K attention partials
    pv_kernel<<<BB * HH * NCH, 256, 0, stream>>>(q_ws, k_ws, v_ws, top_ws,
                                                 mpart_ws, lpart_ws, accpart_ws);
    // K6: output projection (base + broadcast + combine/correct)
    base_kernel<<<(BB * EE) / 4, 256, 0, stream>>>(mean_ws, Wo, bo, base_ws);
    bcast_kernel<<<(BB * LL * EE) / (256 * 4), 256, 0, stream>>>(base_ws, out);
    corr_kernel<<<BB * HH * NT, 256, 0, stream>>>(accpart_ws, lpart_ws, mpart_ws,
                                                  mean_ws, top_ws, Wo, out);
}

// Round 11
// 405.448 us; speedup vs baseline: 1.0014x; 1.0014x over previous
//
#include <hip/hip_runtime.h>
#include <hip/hip_bf16.h>
#include <math.h>

// Problem constants (fixed by reference)
constexpr int BB = 4;
constexpr int LL = 2048;
constexpr int EE = 512;
constexpr int HH = 8;
constexpr int DD = 64;
constexpr int UU = 40;    // sample count
constexpr int NT = 40;    // n_top
constexpr int NCH = 32;   // key chunks (64 keys each) for split-K attention
constexpr int CK = 64;    // keys per chunk
constexpr int MVC = 16;   // L-chunks for meanv stage 1 (128 rows each)
constexpr float NEG_INF = -3.0e38f;

typedef __attribute__((ext_vector_type(8))) short bf8_t;  // 8 bf16 (4 VGPR)
typedef __attribute__((ext_vector_type(4))) float f4_t;   // MFMA C/D frag

// ---------------------------------------------------------------------------
// K1: fused QKV projection via split-bf16 MFMA, 3-product, LEAN pipeline.
// Only the raw float4 prefetch (32 VGPRs) stays live across the MFMA block;
// split2 runs at the top of the next iteration (short, barrier-bounded live
// range for ahu..bmu) -> no scratch spill (R10's 64-reg live set spilled:
// WRITE_SIZE 49->338 MB).
// Tile 128x128x32, 4 waves (2x2 of 64x64), 16x16x32 bf16 MFMA. LDS 32 KB.
// ---------------------------------------------------------------------------
__device__ __forceinline__ void split2(float x, uint& h, uint& m)
{
    uint  xb = __float_as_uint(x);
    uint  hb = (xb + 0x7fffu + ((xb >> 16) & 1u)) & 0xffff0000u;  // RNE bf16
    float r  = x - __uint_as_float(hb);
    h = hb >> 16;
    m = (__float_as_uint(r) & 0xffff0000u) >> 16;                 // trunc
}

__device__ __forceinline__ int swz(int row, int c)
{
    return row * 64 + (((c ^ row ^ (row >> 2)) & 3) << 4);
}

__global__ __launch_bounds__(256, 4) void proj_kernel(
    const float* __restrict__ Xq, const float* __restrict__ Xk, const float* __restrict__ Xv,
    const float* __restrict__ Wq, const float* __restrict__ Wk, const float* __restrict__ Wv,
    const float* __restrict__ bq, const float* __restrict__ bk, const float* __restrict__ bv,
    float* __restrict__ Oq, float* __restrict__ Ok, float* __restrict__ Ov)
{
    const float* X; const float* W; const float* bias; float* O;
    if (blockIdx.z == 0)      { X = Xq; W = Wq; bias = bq; O = Oq; }
    else if (blockIdx.z == 1) { X = Xk; W = Wk; bias = bk; O = Ok; }
    else                      { X = Xv; W = Wv; bias = bv; O = Ov; }

    __shared__ char ldsmem[32768];   // A: hi@0 mid@8192; B likewise in LB
    char* const LA = ldsmem;
    char* const LB = ldsmem + 16384;

    const int tid  = threadIdx.x;
    const int lane = tid & 63;
    const int wave = tid >> 6;
    const int m0 = blockIdx.y * 128;
    const int n0 = blockIdx.x * 128;

    const int srow  = tid >> 1;
    const int shalf = tid & 1;
    const int w0 = swz(srow, shalf * 2);
    const int w1 = swz(srow, shalf * 2 + 1);
    const float* Aptr = X + (size_t)(m0 + srow) * EE + shalf * 16;
    const float* Bptr = W + (size_t)(n0 + srow) * EE + shalf * 16;

    const int rxor = ((((lane >> 4) ^ lane ^ (lane >> 2)) & 3) << 4);
    const int arow = (wave >> 1) * 64 + (lane & 15);
    const int brow = (wave & 1) * 64 + (lane & 15);

    f4_t acc[4][4];
#pragma unroll
    for (int i = 0; i < 4; i++)
#pragma unroll
        for (int j = 0; j < 4; j++) acc[i][j] = (f4_t)0.0f;

    // prefetch registers: ONLY these live across the MFMA block (32 VGPRs)
    float4 fa4[4], fb4[4];
#pragma unroll
    for (int q = 0; q < 4; q++) {
        fa4[q] = *(const float4*)(Aptr + q * 4);
        fb4[q] = *(const float4*)(Bptr + q * 4);
    }

    for (int kt = 0; kt < EE; kt += 32) {
        // split current tile (short live range: consumed by LDS writes below)
        uint ahu[8], amu[8], bhu[8], bmu[8];
#pragma unroll
        for (int p = 0; p < 8; p++) {
            const float a0 = ((const float*)fa4)[2 * p];
            const float a1 = ((const float*)fa4)[2 * p + 1];
            const float b0 = ((const float*)fb4)[2 * p];
            const float b1 = ((const float*)fb4)[2 * p + 1];
            uint h0, m0_, h1, m1_;
            split2(a0, h0, m0_);
            split2(a1, h1, m1_);
            ahu[p] = h0 | (h1 << 16); amu[p] = m0_ | (m1_ << 16);
            split2(b0, h0, m0_);
            split2(b1, h1, m1_);
            bhu[p] = h0 | (h1 << 16); bmu[p] = m0_ | (m1_ << 16);
        }
        __syncthreads();   // previous tile's readers done
        *(uint4*)(LA +     0 + w0) = make_uint4(ahu[0], ahu[1], ahu[2], ahu[3]);
        *(uint4*)(LA +     0 + w1) = make_uint4(ahu[4], ahu[5], ahu[6], ahu[7]);
        *(uint4*)(LA +  8192 + w0) = make_uint4(amu[0], amu[1], amu[2], amu[3]);
        *(uint4*)(LA +  8192 + w1) = make_uint4(amu[4], amu[5], amu[6], amu[7]);
        *(uint4*)(LB +     0 + w0) = make_uint4(bhu[0], bhu[1], bhu[2], bhu[3]);
        *(uint4*)(LB +     0 + w1) = make_uint4(bhu[4], bhu[5], bhu[6], bhu[7]);
        *(uint4*)(LB +  8192 + w0) = make_uint4(bmu[0], bmu[1], bmu[2], bmu[3]);
        *(uint4*)(LB +  8192 + w1) = make_uint4(bmu[4], bmu[5], bmu[6], bmu[7]);
        __syncthreads();   // tile ready

        // prefetch next tile's raw floats; issues under the MFMA block
        if (kt + 32 < EE) {
#pragma unroll
            for (int q = 0; q < 4; q++) {
                fa4[q] = *(const float4*)(Aptr + kt + 32 + q * 4);
                fb4[q] = *(const float4*)(Bptr + kt + 32 + q * 4);
            }
        }

        bf8_t af[4][2];
#pragma unroll
        for (int i = 0; i < 4; i++) {
            const int ro = (arow + i * 16) * 64 + rxor;
            af[i][0] = *(const bf8_t*)(LA +    0 + ro);
            af[i][1] = *(const bf8_t*)(LA + 8192 + ro);
        }
#pragma unroll
        for (int j = 0; j < 4; j++) {
            const int ro = (brow + j * 16) * 64 + rxor;
            bf8_t bh_ = *(const bf8_t*)(LB +    0 + ro);
            bf8_t bm_ = *(const bf8_t*)(LB + 8192 + ro);
#pragma unroll
            for (int i = 0; i < 4; i++) {
                f4_t c = acc[i][j];
                c = __builtin_amdgcn_mfma_f32_16x16x32_bf16(af[i][0], bh_, c, 0, 0, 0); // hh
                c = __builtin_amdgcn_mfma_f32_16x16x32_bf16(af[i][0], bm_, c, 0, 0, 0); // hm
                c = __builtin_amdgcn_mfma_f32_16x16x32_bf16(af[i][1], bh_, c, 0, 0, 0); // mh
                acc[i][j] = c;
            }
        }
    }

#pragma unroll
    for (int j = 0; j < 4; j++) {
        const int n  = n0 + (wave & 1) * 64 + j * 16 + (lane & 15);
        const float bn = bias[n];
        const int h_ = n >> 6, d_ = n & 63;
#pragma unroll
        for (int i = 0; i < 4; i++) {
            const int mb = m0 + (wave >> 1) * 64 + i * 16 + ((lane >> 4) << 2);
#pragma unroll
            for (int r = 0; r < 4; r++) {
                const int m  = mb + r;
                const int b_ = m >> 11;
                const int l_ = m & (LL - 1);
                O[(((size_t)(b_ * HH + h_) * LL + l_) << 6) + d_] = acc[i][j][r] + bn;
            }
        }
    }
}

// ---------------------------------------------------------------------------
// K2a: mean of V stage 1 — 512 blocks = (lchunk 0..15) x (bh 0..31).
// ---------------------------------------------------------------------------
__global__ __launch_bounds__(256) void meanv_part_kernel(const float* __restrict__ v,
                                                         float* __restrict__ vpart)
{
    const int bh    = blockIdx.x & 31;
    const int chunk = blockIdx.x >> 5;
    const int d  = threadIdx.x & 63;
    const int wv = threadIdx.x >> 6;
    const float* base = v + ((size_t)bh * LL + chunk * 128 + wv * 32) * DD + d;
    float acc = 0.0f;
#pragma unroll
    for (int i = 0; i < 32; i++) acc += base[i * DD];
    __shared__ float red[4][DD];
    red[wv][d] = acc;
    __syncthreads();
    if (wv == 0)
        vpart[(size_t)(chunk * 32 + bh) * DD + d]
            = red[0][d] + red[1][d] + red[2][d] + red[3][d];
}

// ---------------------------------------------------------------------------
// K2b: mean of V stage 2 — combine 16 partials per (bh,d).
// ---------------------------------------------------------------------------
__global__ __launch_bounds__(64) void meanv_comb_kernel(const float* __restrict__ vpart,
                                                        float* __restrict__ mean_v)
{
    const int bh = blockIdx.x;
    const int d  = threadIdx.x;
    float s = 0.0f;
#pragma unroll
    for (int c = 0; c < MVC; c++) s += vpart[(size_t)(c * 32 + bh) * DD + d];
    mean_v[bh * DD + d] = s * (1.0f / (float)LL);
}

// ---------------------------------------------------------------------------
// K3: sparsity measure M[b,h,l] = max_s(q.k_sample) - sum_s(q.k_sample)/L
// One wave per (b,h,l). Lane map: 8 samples x 8 d-chunks. XCD-swizzled grid.
// ---------------------------------------------------------------------------
__global__ __launch_bounds__(256) void measure_kernel(const float* __restrict__ q,
                                                      const float* __restrict__ k,
                                                      const int* __restrict__ idx_sample,
                                                      float* __restrict__ M)
{
    int bh   = blockIdx.x & 31;
    int lc   = blockIdx.x >> 5;
    int lane = threadIdx.x & 63;
    int wv   = threadIdx.x >> 6;
    int l    = lc * 4 + wv;
    int s8   = lane >> 3;   // sample slot 0..7
    int c    = lane & 7;    // d-chunk 0..7

    const float* qrow = q + ((size_t)bh * LL + l) * DD + c * 8;
    float4 q0 = *(const float4*)(qrow);
    float4 q1 = *(const float4*)(qrow + 4);

    const float* kbase = k + (size_t)bh * LL * DD;
    const int*   irow  = idx_sample + l * UU;

    float mx = NEG_INF, sum = 0.0f;
#pragma unroll
    for (int it = 0; it < UU; it += 8) {
        int ki = irow[it + s8];
        const float* krow = kbase + (size_t)ki * DD + c * 8;
        float4 k0 = *(const float4*)(krow);
        float4 k1 = *(const float4*)(krow + 4);
        float p = q0.x*k0.x + q0.y*k0.y + q0.z*k0.z + q0.w*k0.w
                + q1.x*k1.x + q1.y*k1.y + q1.z*k1.z + q1.w*k1.w;
        p += __shfl_xor(p, 1, 64);
        p += __shfl_xor(p, 2, 64);
        p += __shfl_xor(p, 4, 64);
        mx = fmaxf(mx, p);
        sum += p;
    }
    mx  = fmaxf(mx, __shfl_xor(mx, 8, 64));
    sum += __shfl_xor(sum, 8, 64);
    mx  = fmaxf(mx, __shfl_xor(mx, 16, 64));
    sum += __shfl_xor(sum, 16, 64);
    mx  = fmaxf(mx, __shfl_xor(mx, 32, 64));
    sum += __shfl_xor(sum, 32, 64);

    if (lane == 0) M[bh * LL + l] = mx - sum * (1.0f / (float)LL);
}

// ---------------------------------------------------------------------------
// K4: top-40 per (b,h), single-wave register version.
// ---------------------------------------------------------------------------
__global__ __launch_bounds__(64) void topk_kernel(const float* __restrict__ M,
                                                  int* __restrict__ top)
{
    const int bh   = blockIdx.x;
    const int lane = threadIdx.x;

    unsigned long long keys[32];
#pragma unroll
    for (int i = 0; i < 32; i++) {
        int idx = i * 64 + lane;
        uint u  = __float_as_uint(M[bh * LL + idx]);
        uint sv = (u & 0x80000000u) ? ~u : (u | 0x80000000u);
        keys[i] = ((unsigned long long)sv << 32) | (uint)(LL - 1 - idx);
    }
    unsigned long long lmax = 0ull;
#pragma unroll
    for (int i = 0; i < 32; i++) lmax = (keys[i] > lmax) ? keys[i] : lmax;

    for (int it = 0; it < NT; it++) {
        unsigned long long g = lmax;
#pragma unroll
        for (int off = 1; off < 64; off <<= 1) {
            unsigned long long o = __shfl_xor(g, off, 64);
            g = (o > g) ? o : g;
        }
        if (lane == 0) top[bh * NT + it] = LL - 1 - (int)(g & 0xffffffffu);
#pragma unroll
        for (int i = 0; i < 32; i++) if (keys[i] == g) keys[i] = 0ull;
        lmax = 0ull;
#pragma unroll
        for (int i = 0; i < 32; i++) lmax = (keys[i] > lmax) ? keys[i] : lmax;
    }
}

// ---------------------------------------------------------------------------
// K5: flash-style split-K attention partials.
// ---------------------------------------------------------------------------
__global__ __launch_bounds__(256) void pv_kernel(const float* __restrict__ q,
                                                 const float* __restrict__ k,
                                                 const float* __restrict__ v,
                                                 const int* __restrict__ top,
                                                 float* __restrict__ mpart,
                                                 float* __restrict__ lpart,
                                                 float* __restrict__ accpart)
{
    const int bh    = blockIdx.x & 31;
    const int chunk = blockIdx.x >> 5;
    const int tid   = threadIdx.x;
    const int lane  = tid & 63, wv = tid >> 6;

    __shared__ float qs[NT][DD];        // 10240 B
    __shared__ float sc[NT][CK + 4];    // 10880 B

    for (int i = tid; i < NT * DD / 4; i += 256) {
        int u  = i >> 4;
        int d4 = (i & 15) * 4;
        int l  = top[bh * NT + u];
        *(float4*)&qs[u][d4] = *(const float4*)(q + ((size_t)bh * LL + l) * DD + d4);
    }
    __syncthreads();

    {
        const int key  = tid >> 2;
        const int dseg = tid & 3;
        const float* krow = k + ((size_t)bh * LL + chunk * CK + key) * DD + dseg * 16;
        float4 k0 = *(const float4*)(krow);
        float4 k1 = *(const float4*)(krow + 4);
        float4 k2 = *(const float4*)(krow + 8);
        float4 k3 = *(const float4*)(krow + 12);
#pragma unroll 8
        for (int u = 0; u < NT; u++) {
            const float* qrow = &qs[u][dseg * 16];
            float4 q0 = *(const float4*)(qrow);
            float4 q1 = *(const float4*)(qrow + 4);
            float4 q2 = *(const float4*)(qrow + 8);
            float4 q3 = *(const float4*)(qrow + 12);
            float p = k0.x*q0.x + k0.y*q0.y + k0.z*q0.z + k0.w*q0.w
                    + k1.x*q1.x + k1.y*q1.y + k1.z*q1.z + k1.w*q1.w
                    + k2.x*q2.x + k2.y*q2.y + k2.z*q2.z + k2.w*q2.w
                    + k3.x*q3.x + k3.y*q3.y + k3.z*q3.z + k3.w*q3.w;
            p += __shfl_xor(p, 1, 64);
            p += __shfl_xor(p, 2, 64);
            if (dseg == 0) sc[u][key] = p;
        }
    }
    __syncthreads();

#pragma unroll
    for (int i = 0; i < 10; i++) {
        const int u = wv * 10 + i;
        float val = sc[u][lane];
        float mx = val;
        mx = fmaxf(mx, __shfl_xor(mx, 1, 64));
        mx = fmaxf(mx, __shfl_xor(mx, 2, 64));
        mx = fmaxf(mx, __shfl_xor(mx, 4, 64));
        mx = fmaxf(mx, __shfl_xor(mx, 8, 64));
        mx = fmaxf(mx, __shfl_xor(mx, 16, 64));
        mx = fmaxf(mx, __shfl_xor(mx, 32, 64));
        float e = __expf(val - mx);
        sc[u][lane] = e;
        float s = e;
        s += __shfl_xor(s, 1, 64);
        s += __shfl_xor(s, 2, 64);
        s += __shfl_xor(s, 4, 64);
        s += __shfl_xor(s, 8, 64);
        s += __shfl_xor(s, 16, 64);
        s += __shfl_xor(s, 32, 64);
        if (lane == 0) {
            mpart[(bh * NCH + chunk) * NT + u] = mx;
            lpart[(bh * NCH + chunk) * NT + u] = s;
        }
    }
    __syncthreads();

    {
        float pacc[10];
#pragma unroll
        for (int i = 0; i < 10; i++) pacc[i] = 0.0f;
        const float* vbase = v + ((size_t)bh * LL + chunk * CK) * DD;
#pragma unroll 8
        for (int t = 0; t < CK; t++) {
            float vval = vbase[(size_t)t * DD + lane];
#pragma unroll
            for (int i = 0; i < 10; i++) pacc[i] += sc[wv * 10 + i][t] * vval;
        }
#pragma unroll
        for (int i = 0; i < 10; i++) {
            const int u = wv * 10 + i;
            accpart[(((size_t)(bh * NCH + chunk)) * NT + u) * 64 + lane] = pacc[i];
        }
    }
}

// ---------------------------------------------------------------------------
// K6a: base output row per batch: base[b,e] = meanctx[b,:] . Wo[e,:] + bo[e]
// ---------------------------------------------------------------------------
__global__ __launch_bounds__(256) void base_kernel(const float* __restrict__ mean_v,
                                                   const float* __restrict__ Wo,
                                                   const float* __restrict__ bo,
                                                   float* __restrict__ base)
{
    int lane = threadIdx.x & 63, wv = threadIdx.x >> 6;
    int be = blockIdx.x * 4 + wv;
    int b  = be >> 9;
    int e  = be & (EE - 1);
    const float* mrow = mean_v + b * EE;
    const float* wrow = Wo + (size_t)e * EE;
    float acc = 0.0f;
#pragma unroll
    for (int j = 0; j < 8; j++) acc += mrow[lane + j * 64] * wrow[lane + j * 64];
#pragma unroll
    for (int off = 32; off > 0; off >>= 1) acc += __shfl_down(acc, off, 64);
    if (lane == 0) base[be] = acc + bo[e];
}

// ---------------------------------------------------------------------------
// K6b: broadcast base row to all l
// ---------------------------------------------------------------------------
__global__ __launch_bounds__(256) void bcast_kernel(const float* __restrict__ base,
                                                    float* __restrict__ out)
{
    size_t fi = ((size_t)blockIdx.x * 256 + threadIdx.x) * 4;
    int b  = (int)(fi >> 20);
    int e4 = (int)(fi & (EE - 1));
    float4 val = *(const float4*)(base + b * EE + e4);
    *(float4*)(out + fi) = val;
}

// ---------------------------------------------------------------------------
// K6c: combine chunk partials (online-softmax merge) + correction GEMV.
// ---------------------------------------------------------------------------
__global__ __launch_bounds__(256) void corr_kernel(const float* __restrict__ accpart,
                                                   const float* __restrict__ lpart,
                                                   const float* __restrict__ mpart,
                                                   const float* __restrict__ mean_v,
                                                   const int* __restrict__ top,
                                                   const float* __restrict__ Wo,
                                                   float* __restrict__ out)
{
    int bhu = blockIdx.x;
    int bh  = bhu / NT;
    int u   = bhu % NT;
    int h   = bh & (HH - 1);
    int b   = bh >> 3;
    int tid = threadIdx.x;
    int l   = top[bhu];

    __shared__ float delta[DD];
    if (tid < DD) {
        float m = NEG_INF;
#pragma unroll 8
        for (int c = 0; c < NCH; c++) m = fmaxf(m, mpart[(bh * NCH + c) * NT + u]);
        float den = 0.0f, num = 0.0f;
#pragma unroll 8
        for (int c = 0; c < NCH; c++) {
            float f = __expf(mpart[(bh * NCH + c) * NT + u] - m);
            den += lpart[(bh * NCH + c) * NT + u] * f;
            num += accpart[(((size_t)(bh * NCH + c)) * NT + u) * 64 + tid] * f;
        }
        delta[tid] = num / den - mean_v[bh * DD + tid];
    }
    __syncthreads();

    float* orow = out + ((size_t)(b * LL + l)) * EE;
#pragma unroll
    for (int rep = 0; rep < 2; rep++) {
        int e = tid + rep * 256;
        const float* wrow = Wo + (size_t)e * EE + h * DD;
        float acc = 0.0f;
#pragma unroll
        for (int d = 0; d < DD; d++) acc += delta[d] * wrow[d];
        atomicAdd(orow + e, acc);
    }
}

// ---------------------------------------------------------------------------
extern "C" void kernel_launch(void* const* d_in, const int* in_sizes, int n_in,
                              void* d_out, int out_size, void* d_ws, size_t ws_size,
                              hipStream_t stream)
{
    const float* query = (const float*)d_in[0];
    const float* key   = (const float*)d_in[1];
    const float* value = (const float*)d_in[2];
    const int*   idxs  = (const int*)d_in[3];
    const float* Wq = (const float*)d_in[4];
    const float* bq = (const float*)d_in[5];
    const float* Wk = (const float*)d_in[6];
    const float* bk = (const float*)d_in[7];
    const float* Wv = (const float*)d_in[8];
    const float* bv = (const float*)d_in[9];
    const float* Wo = (const float*)d_in[10];
    const float* bo = (const float*)d_in[11];
    float* out = (float*)d_out;

    // workspace layout (~62 MB)
    char* ws = (char*)d_ws;
    size_t off = 0;
    const size_t qkv_bytes = (size_t)BB * HH * LL * DD * sizeof(float); // 16 MB each
    float* q_ws = (float*)(ws + off); off += qkv_bytes;
    float* k_ws = (float*)(ws + off); off += qkv_bytes;
    float* v_ws = (float*)(ws + off); off += qkv_bytes;
    float* M_ws    = (float*)(ws + off); off += (size_t)BB * HH * LL * sizeof(float);
    int*   top_ws  = (int*)(ws + off);   off += (size_t)BB * HH * NT * sizeof(int);
    float* mean_ws = (float*)(ws + off); off += (size_t)BB * HH * DD * sizeof(float);
    float* vpart_ws = (float*)(ws + off); off += (size_t)BB * HH * MVC * DD * sizeof(float);
    float* mpart_ws = (float*)(ws + off); off += (size_t)BB * HH * NCH * NT * sizeof(float);
    float* lpart_ws = (float*)(ws + off); off += (size_t)BB * HH * NCH * NT * sizeof(float);
    float* accpart_ws = (float*)(ws + off); off += (size_t)BB * HH * NCH * NT * DD * sizeof(float);
    float* base_ws = (float*)(ws + off); off += (size_t)BB * EE * sizeof(float);

    // K1: QKV projections (split-bf16 MFMA, 3 products, lean pipeline)
    dim3 g1(EE / 128, (BB * LL) / 128, 3);
    proj_kernel<<<g1, 256, 0, stream>>>(query, key, value, Wq, Wk, Wv, bq, bk, bv,
                                        q_ws, k_ws, v_ws);
    // K2: mean of V (two-stage)
    meanv_part_kernel<<<BB * HH * MVC, 256, 0, stream>>>(v_ws, vpart_ws);
    meanv_comb_kernel<<<BB * HH, 64, 0, stream>>>(vpart_ws, mean_ws);
    // K3: sparsity measure (XCD-swizzled grid)
    measure_kernel<<<(LL / 4) * 32, 256, 0, stream>>>(q_ws, k_ws, idxs, M_ws);
    // K4: top-40 (single wave per bh)
    topk_kernel<<<BB * HH, 64, 0, stream>>>(M_ws, top_ws);
    // K5: split-K attention partials
    pv_kernel<<<BB * HH * NCH, 256, 0, stream>>>(q_ws, k_ws, v_ws, top_ws,
                                                 mpart_ws, lpart_ws, accpart_ws);
    // K6: output projection (base + broadcast + combine/correct)
    base_kernel<<<(BB * EE) / 4, 256, 0, stream>>>(mean_ws, Wo, bo, base_ws);
    bcast_kernel<<<(BB * LL * EE) / (256 * 4), 256, 0, stream>>>(base_ws, out);
    corr_kernel<<<BB * HH * NT, 256, 0, stream>>>(accpart_ws, lpart_ws, mpart_ws,
                                                  mean_ws, top_ws, Wo, out);
}

// Round 12
// 308.714 us; speedup vs baseline: 1.3152x; 1.3133x over previous
//
#include <hip/hip_runtime.h>
#include <hip/hip_bf16.h>
#include <math.h>

// Problem constants (fixed by reference)
constexpr int BB = 4;
constexpr int LL = 2048;
constexpr int EE = 512;
constexpr int HH = 8;
constexpr int DD = 64;
constexpr int UU = 40;    // sample count
constexpr int NT = 40;    // n_top
constexpr int NCH = 32;   // key chunks (64 keys each) for split-K attention
constexpr int CK = 64;    // keys per chunk
constexpr int MVC = 16;   // L-chunks for meanv stage 1 (128 rows each)
constexpr float NEG_INF = -3.0e38f;

typedef __attribute__((ext_vector_type(8))) short bf8_t;  // 8 bf16 (4 VGPR)
typedef __attribute__((ext_vector_type(4))) float f4_t;   // MFMA C/D frag

// ---------------------------------------------------------------------------
// K1: fused QKV projection via split-bf16 MFMA, 3-product (R9 body, reverted:
// R10/R11 prefetch-across-MFMA variants spilled to scratch — WRITE_SIZE
// 49->338 MB — because acc(64)+af(32)+misc ~120 VGPR leaves no room under
// the 128-reg cap of __launch_bounds__(256,4)).
// f32 = hi(RNE bf16) + mid(trunc bf16); products hh+hm+mh.
// Tile 128x128x32, 4 waves (2x2 of 64x64), 16x16x32 bf16 MFMA. LDS 32 KB.
// ---------------------------------------------------------------------------
__device__ __forceinline__ void split2(float x, uint& h, uint& m)
{
    uint  xb = __float_as_uint(x);
    uint  hb = (xb + 0x7fffu + ((xb >> 16) & 1u)) & 0xffff0000u;  // RNE bf16
    float r  = x - __uint_as_float(hb);
    h = hb >> 16;
    m = (__float_as_uint(r) & 0xffff0000u) >> 16;                 // trunc
}

__device__ __forceinline__ int swz(int row, int c)
{
    return row * 64 + (((c ^ row ^ (row >> 2)) & 3) << 4);
}

__global__ __launch_bounds__(256, 4) void proj_kernel(
    const float* __restrict__ Xq, const float* __restrict__ Xk, const float* __restrict__ Xv,
    const float* __restrict__ Wq, const float* __restrict__ Wk, const float* __restrict__ Wv,
    const float* __restrict__ bq, const float* __restrict__ bk, const float* __restrict__ bv,
    float* __restrict__ Oq, float* __restrict__ Ok, float* __restrict__ Ov)
{
    const float* X; const float* W; const float* bias; float* O;
    if (blockIdx.z == 0)      { X = Xq; W = Wq; bias = bq; O = Oq; }
    else if (blockIdx.z == 1) { X = Xk; W = Wk; bias = bk; O = Ok; }
    else                      { X = Xv; W = Wv; bias = bv; O = Ov; }

    __shared__ char ldsmem[32768];   // A: hi@0 mid@8192; B likewise in LB
    char* const LA = ldsmem;
    char* const LB = ldsmem + 16384;

    const int tid  = threadIdx.x;
    const int lane = tid & 63;
    const int wave = tid >> 6;
    const int m0 = blockIdx.y * 128;
    const int n0 = blockIdx.x * 128;

    const int srow  = tid >> 1;
    const int shalf = tid & 1;
    const int w0 = swz(srow, shalf * 2);
    const int w1 = swz(srow, shalf * 2 + 1);
    const float* Aptr = X + (size_t)(m0 + srow) * EE + shalf * 16;
    const float* Bptr = W + (size_t)(n0 + srow) * EE + shalf * 16;

    const int rxor = ((((lane >> 4) ^ lane ^ (lane >> 2)) & 3) << 4);
    const int arow = (wave >> 1) * 64 + (lane & 15);
    const int brow = (wave & 1) * 64 + (lane & 15);

    f4_t acc[4][4];
#pragma unroll
    for (int i = 0; i < 4; i++)
#pragma unroll
        for (int j = 0; j < 4; j++) acc[i][j] = (f4_t)0.0f;

    for (int kt = 0; kt < EE; kt += 32) {
        float fa[16], fb[16];
#pragma unroll
        for (int q = 0; q < 4; q++) {
            *(float4*)(fa + q * 4) = *(const float4*)(Aptr + kt + q * 4);
            *(float4*)(fb + q * 4) = *(const float4*)(Bptr + kt + q * 4);
        }
        uint ahu[8], amu[8], bhu[8], bmu[8];
#pragma unroll
        for (int p = 0; p < 8; p++) {
            uint h0, m0_, h1, m1_;
            split2(fa[2 * p], h0, m0_);
            split2(fa[2 * p + 1], h1, m1_);
            ahu[p] = h0 | (h1 << 16); amu[p] = m0_ | (m1_ << 16);
            split2(fb[2 * p], h0, m0_);
            split2(fb[2 * p + 1], h1, m1_);
            bhu[p] = h0 | (h1 << 16); bmu[p] = m0_ | (m1_ << 16);
        }
        __syncthreads();
        *(uint4*)(LA +     0 + w0) = make_uint4(ahu[0], ahu[1], ahu[2], ahu[3]);
        *(uint4*)(LA +     0 + w1) = make_uint4(ahu[4], ahu[5], ahu[6], ahu[7]);
        *(uint4*)(LA +  8192 + w0) = make_uint4(amu[0], amu[1], amu[2], amu[3]);
        *(uint4*)(LA +  8192 + w1) = make_uint4(amu[4], amu[5], amu[6], amu[7]);
        *(uint4*)(LB +     0 + w0) = make_uint4(bhu[0], bhu[1], bhu[2], bhu[3]);
        *(uint4*)(LB +     0 + w1) = make_uint4(bhu[4], bhu[5], bhu[6], bhu[7]);
        *(uint4*)(LB +  8192 + w0) = make_uint4(bmu[0], bmu[1], bmu[2], bmu[3]);
        *(uint4*)(LB +  8192 + w1) = make_uint4(bmu[4], bmu[5], bmu[6], bmu[7]);
        __syncthreads();

        bf8_t af[4][2];
#pragma unroll
        for (int i = 0; i < 4; i++) {
            const int ro = (arow + i * 16) * 64 + rxor;
            af[i][0] = *(const bf8_t*)(LA +    0 + ro);
            af[i][1] = *(const bf8_t*)(LA + 8192 + ro);
        }
#pragma unroll
        for (int j = 0; j < 4; j++) {
            const int ro = (brow + j * 16) * 64 + rxor;
            bf8_t bh_ = *(const bf8_t*)(LB +    0 + ro);
            bf8_t bm_ = *(const bf8_t*)(LB + 8192 + ro);
#pragma unroll
            for (int i = 0; i < 4; i++) {
                f4_t c = acc[i][j];
                c = __builtin_amdgcn_mfma_f32_16x16x32_bf16(af[i][0], bh_, c, 0, 0, 0); // hh
                c = __builtin_amdgcn_mfma_f32_16x16x32_bf16(af[i][0], bm_, c, 0, 0, 0); // hm
                c = __builtin_amdgcn_mfma_f32_16x16x32_bf16(af[i][1], bh_, c, 0, 0, 0); // mh
                acc[i][j] = c;
            }
        }
    }

#pragma unroll
    for (int j = 0; j < 4; j++) {
        const int n  = n0 + (wave & 1) * 64 + j * 16 + (lane & 15);
        const float bn = bias[n];
        const int h_ = n >> 6, d_ = n & 63;
#pragma unroll
        for (int i = 0; i < 4; i++) {
            const int mb = m0 + (wave >> 1) * 64 + i * 16 + ((lane >> 4) << 2);
#pragma unroll
            for (int r = 0; r < 4; r++) {
                const int m  = mb + r;
                const int b_ = m >> 11;
                const int l_ = m & (LL - 1);
                O[(((size_t)(b_ * HH + h_) * LL + l_) << 6) + d_] = acc[i][j][r] + bn;
            }
        }
    }
}

// ---------------------------------------------------------------------------
// K2a: mean of V stage 1 — 512 blocks = (lchunk 0..15) x (bh 0..31).
// ---------------------------------------------------------------------------
__global__ __launch_bounds__(256) void meanv_part_kernel(const float* __restrict__ v,
                                                         float* __restrict__ vpart)
{
    const int bh    = blockIdx.x & 31;
    const int chunk = blockIdx.x >> 5;
    const int d  = threadIdx.x & 63;
    const int wv = threadIdx.x >> 6;
    const float* base = v + ((size_t)bh * LL + chunk * 128 + wv * 32) * DD + d;
    float acc = 0.0f;
#pragma unroll
    for (int i = 0; i < 32; i++) acc += base[i * DD];
    __shared__ float red[4][DD];
    red[wv][d] = acc;
    __syncthreads();
    if (wv == 0)
        vpart[(size_t)(chunk * 32 + bh) * DD + d]
            = red[0][d] + red[1][d] + red[2][d] + red[3][d];
}

// ---------------------------------------------------------------------------
// K2b: mean of V stage 2 — combine 16 partials per (bh,d).
// ---------------------------------------------------------------------------
__global__ __launch_bounds__(64) void meanv_comb_kernel(const float* __restrict__ vpart,
                                                        float* __restrict__ mean_v)
{
    const int bh = blockIdx.x;
    const int d  = threadIdx.x;
    float s = 0.0f;
#pragma unroll
    for (int c = 0; c < MVC; c++) s += vpart[(size_t)(c * 32 + bh) * DD + d];
    mean_v[bh * DD + d] = s * (1.0f / (float)LL);
}

// ---------------------------------------------------------------------------
// K3: sparsity measure M[b,h,l] = max_s(q.k_sample) - sum_s(q.k_sample)/L
// One wave per (b,h,l). Lane map: 8 samples x 8 d-chunks. XCD-swizzled grid.
// ---------------------------------------------------------------------------
__global__ __launch_bounds__(256) void measure_kernel(const float* __restrict__ q,
                                                      const float* __restrict__ k,
                                                      const int* __restrict__ idx_sample,
                                                      float* __restrict__ M)
{
    int bh   = blockIdx.x & 31;
    int lc   = blockIdx.x >> 5;
    int lane = threadIdx.x & 63;
    int wv   = threadIdx.x >> 6;
    int l    = lc * 4 + wv;
    int s8   = lane >> 3;   // sample slot 0..7
    int c    = lane & 7;    // d-chunk 0..7

    const float* qrow = q + ((size_t)bh * LL + l) * DD + c * 8;
    float4 q0 = *(const float4*)(qrow);
    float4 q1 = *(const float4*)(qrow + 4);

    const float* kbase = k + (size_t)bh * LL * DD;
    const int*   irow  = idx_sample + l * UU;

    float mx = NEG_INF, sum = 0.0f;
#pragma unroll
    for (int it = 0; it < UU; it += 8) {
        int ki = irow[it + s8];
        const float* krow = kbase + (size_t)ki * DD + c * 8;
        float4 k0 = *(const float4*)(krow);
        float4 k1 = *(const float4*)(krow + 4);
        float p = q0.x*k0.x + q0.y*k0.y + q0.z*k0.z + q0.w*k0.w
                + q1.x*k1.x + q1.y*k1.y + q1.z*k1.z + q1.w*k1.w;
        p += __shfl_xor(p, 1, 64);
        p += __shfl_xor(p, 2, 64);
        p += __shfl_xor(p, 4, 64);
        mx = fmaxf(mx, p);
        sum += p;
    }
    mx  = fmaxf(mx, __shfl_xor(mx, 8, 64));
    sum += __shfl_xor(sum, 8, 64);
    mx  = fmaxf(mx, __shfl_xor(mx, 16, 64));
    sum += __shfl_xor(sum, 16, 64);
    mx  = fmaxf(mx, __shfl_xor(mx, 32, 64));
    sum += __shfl_xor(sum, 32, 64);

    if (lane == 0) M[bh * LL + l] = mx - sum * (1.0f / (float)LL);
}

// ---------------------------------------------------------------------------
// K4: top-40 per (b,h), single-wave register version.
// ---------------------------------------------------------------------------
__global__ __launch_bounds__(64) void topk_kernel(const float* __restrict__ M,
                                                  int* __restrict__ top)
{
    const int bh   = blockIdx.x;
    const int lane = threadIdx.x;

    unsigned long long keys[32];
#pragma unroll
    for (int i = 0; i < 32; i++) {
        int idx = i * 64 + lane;
        uint u  = __float_as_uint(M[bh * LL + idx]);
        uint sv = (u & 0x80000000u) ? ~u : (u | 0x80000000u);
        keys[i] = ((unsigned long long)sv << 32) | (uint)(LL - 1 - idx);
    }
    unsigned long long lmax = 0ull;
#pragma unroll
    for (int i = 0; i < 32; i++) lmax = (keys[i] > lmax) ? keys[i] : lmax;

    for (int it = 0; it < NT; it++) {
        unsigned long long g = lmax;
#pragma unroll
        for (int off = 1; off < 64; off <<= 1) {
            unsigned long long o = __shfl_xor(g, off, 64);
            g = (o > g) ? o : g;
        }
        if (lane == 0) top[bh * NT + it] = LL - 1 - (int)(g & 0xffffffffu);
#pragma unroll
        for (int i = 0; i < 32; i++) if (keys[i] == g) keys[i] = 0ull;
        lmax = 0ull;
#pragma unroll
        for (int i = 0; i < 32; i++) lmax = (keys[i] > lmax) ? keys[i] : lmax;
    }
}

// ---------------------------------------------------------------------------
// K5: flash-style split-K attention partials.
// ---------------------------------------------------------------------------
__global__ __launch_bounds__(256) void pv_kernel(const float* __restrict__ q,
                                                 const float* __restrict__ k,
                                                 const float* __restrict__ v,
                                                 const int* __restrict__ top,
                                                 float* __restrict__ mpart,
                                                 float* __restrict__ lpart,
                                                 float* __restrict__ accpart)
{
    const int bh    = blockIdx.x & 31;
    const int chunk = blockIdx.x >> 5;
    const int tid   = threadIdx.x;
    const int lane  = tid & 63, wv = tid >> 6;

    __shared__ float qs[NT][DD];        // 10240 B
    __shared__ float sc[NT][CK + 4];    // 10880 B

    for (int i = tid; i < NT * DD / 4; i += 256) {
        int u  = i >> 4;
        int d4 = (i & 15) * 4;
        int l  = top[bh * NT + u];
        *(float4*)&qs[u][d4] = *(const float4*)(q + ((size_t)bh * LL + l) * DD + d4);
    }
    __syncthreads();

    {
        const int key  = tid >> 2;
        const int dseg = tid & 3;
        const float* krow = k + ((size_t)bh * LL + chunk * CK + key) * DD + dseg * 16;
        float4 k0 = *(const float4*)(krow);
        float4 k1 = *(const float4*)(krow + 4);
        float4 k2 = *(const float4*)(krow + 8);
        float4 k3 = *(const float4*)(krow + 12);
#pragma unroll 8
        for (int u = 0; u < NT; u++) {
            const float* qrow = &qs[u][dseg * 16];
            float4 q0 = *(const float4*)(qrow);
            float4 q1 = *(const float4*)(qrow + 4);
            float4 q2 = *(const float4*)(qrow + 8);
            float4 q3 = *(const float4*)(qrow + 12);
            float p = k0.x*q0.x + k0.y*q0.y + k0.z*q0.z + k0.w*q0.w
                    + k1.x*q1.x + k1.y*q1.y + k1.z*q1.z + k1.w*q1.w
                    + k2.x*q2.x + k2.y*q2.y + k2.z*q2.z + k2.w*q2.w
                    + k3.x*q3.x + k3.y*q3.y + k3.z*q3.z + k3.w*q3.w;
            p += __shfl_xor(p, 1, 64);
            p += __shfl_xor(p, 2, 64);
            if (dseg == 0) sc[u][key] = p;
        }
    }
    __syncthreads();

#pragma unroll
    for (int i = 0; i < 10; i++) {
        const int u = wv * 10 + i;
        float val = sc[u][lane];
        float mx = val;
        mx = fmaxf(mx, __shfl_xor(mx, 1, 64));
        mx = fmaxf(mx, __shfl_xor(mx, 2, 64));
        mx = fmaxf(mx, __shfl_xor(mx, 4, 64));
        mx = fmaxf(mx, __shfl_xor(mx, 8, 64));
        mx = fmaxf(mx, __shfl_xor(mx, 16, 64));
        mx = fmaxf(mx, __shfl_xor(mx, 32, 64));
        float e = __expf(val - mx);
        sc[u][lane] = e;
        float s = e;
        s += __shfl_xor(s, 1, 64);
        s += __shfl_xor(s, 2, 64);
        s += __shfl_xor(s, 4, 64);
        s += __shfl_xor(s, 8, 64);
        s += __shfl_xor(s, 16, 64);
        s += __shfl_xor(s, 32, 64);
        if (lane == 0) {
            mpart[(bh * NCH + chunk) * NT + u] = mx;
            lpart[(bh * NCH + chunk) * NT + u] = s;
        }
    }
    __syncthreads();

    {
        float pacc[10];
#pragma unroll
        for (int i = 0; i < 10; i++) pacc[i] = 0.0f;
        const float* vbase = v + ((size_t)bh * LL + chunk * CK) * DD;
#pragma unroll 8
        for (int t = 0; t < CK; t++) {
            float vval = vbase[(size_t)t * DD + lane];
#pragma unroll
            for (int i = 0; i < 10; i++) pacc[i] += sc[wv * 10 + i][t] * vval;
        }
#pragma unroll
        for (int i = 0; i < 10; i++) {
            const int u = wv * 10 + i;
            accpart[(((size_t)(bh * NCH + chunk)) * NT + u) * 64 + lane] = pacc[i];
        }
    }
}

// ---------------------------------------------------------------------------
// K6a: base output row per batch: base[b,e] = meanctx[b,:] . Wo[e,:] + bo[e]
// ---------------------------------------------------------------------------
__global__ __launch_bounds__(256) void base_kernel(const float* __restrict__ mean_v,
                                                   const float* __restrict__ Wo,
                                                   const float* __restrict__ bo,
                                                   float* __restrict__ base)
{
    int lane = threadIdx.x & 63, wv = threadIdx.x >> 6;
    int be = blockIdx.x * 4 + wv;
    int b  = be >> 9;
    int e  = be & (EE - 1);
    const float* mrow = mean_v + b * EE;
    const float* wrow = Wo + (size_t)e * EE;
    float acc = 0.0f;
#pragma unroll
    for (int j = 0; j < 8; j++) acc += mrow[lane + j * 64] * wrow[lane + j * 64];
#pragma unroll
    for (int off = 32; off > 0; off >>= 1) acc += __shfl_down(acc, off, 64);
    if (lane == 0) base[be] = acc + bo[e];
}

// ---------------------------------------------------------------------------
// K6b: broadcast base row to all l
// ---------------------------------------------------------------------------
__global__ __launch_bounds__(256) void bcast_kernel(const float* __restrict__ base,
                                                    float* __restrict__ out)
{
    size_t fi = ((size_t)blockIdx.x * 256 + threadIdx.x) * 4;
    int b  = (int)(fi >> 20);
    int e4 = (int)(fi & (EE - 1));
    float4 val = *(const float4*)(base + b * EE + e4);
    *(float4*)(out + fi) = val;
}

// ---------------------------------------------------------------------------
// K6c: combine chunk partials (online-softmax merge) + correction GEMV.
// ---------------------------------------------------------------------------
__global__ __launch_bounds__(256) void corr_kernel(const float* __restrict__ accpart,
                                                   const float* __restrict__ lpart,
                                                   const float* __restrict__ mpart,
                                                   const float* __restrict__ mean_v,
                                                   const int* __restrict__ top,
                                                   const float* __restrict__ Wo,
                                                   float* __restrict__ out)
{
    int bhu = blockIdx.x;
    int bh  = bhu / NT;
    int u   = bhu % NT;
    int h   = bh & (HH - 1);
    int b   = bh >> 3;
    int tid = threadIdx.x;
    int l   = top[bhu];

    __shared__ float delta[DD];
    if (tid < DD) {
        float m = NEG_INF;
#pragma unroll 8
        for (int c = 0; c < NCH; c++) m = fmaxf(m, mpart[(bh * NCH + c) * NT + u]);
        float den = 0.0f, num = 0.0f;
#pragma unroll 8
        for (int c = 0; c < NCH; c++) {
            float f = __expf(mpart[(bh * NCH + c) * NT + u] - m);
            den += lpart[(bh * NCH + c) * NT + u] * f;
            num += accpart[(((size_t)(bh * NCH + c)) * NT + u) * 64 + tid] * f;
        }
        delta[tid] = num / den - mean_v[bh * DD + tid];
    }
    __syncthreads();

    float* orow = out + ((size_t)(b * LL + l)) * EE;
#pragma unroll
    for (int rep = 0; rep < 2; rep++) {
        int e = tid + rep * 256;
        const float* wrow = Wo + (size_t)e * EE + h * DD;
        float acc = 0.0f;
#pragma unroll
        for (int d = 0; d < DD; d++) acc += delta[d] * wrow[d];
        atomicAdd(orow + e, acc);
    }
}

// ---------------------------------------------------------------------------
extern "C" void kernel_launch(void* const* d_in, const int* in_sizes, int n_in,
                              void* d_out, int out_size, void* d_ws, size_t ws_size,
                              hipStream_t stream)
{
    const float* query = (const float*)d_in[0];
    const float* key   = (const float*)d_in[1];
    const float* value = (const float*)d_in[2];
    const int*   idxs  = (const int*)d_in[3];
    const float* Wq = (const float*)d_in[4];
    const float* bq = (const float*)d_in[5];
    const float* Wk = (const float*)d_in[6];
    const float* bk = (const float*)d_in[7];
    const float* Wv = (const float*)d_in[8];
    const float* bv = (const float*)d_in[9];
    const float* Wo = (const float*)d_in[10];
    const float* bo = (const float*)d_in[11];
    float* out = (float*)d_out;

    // workspace layout (~62 MB)
    char* ws = (char*)d_ws;
    size_t off = 0;
    const size_t qkv_bytes = (size_t)BB * HH * LL * DD * sizeof(float); // 16 MB each
    float* q_ws = (float*)(ws + off); off += qkv_bytes;
    float* k_ws = (float*)(ws + off); off += qkv_bytes;
    float* v_ws = (float*)(ws + off); off += qkv_bytes;
    float* M_ws    = (float*)(ws + off); off += (size_t)BB * HH * LL * sizeof(float);
    int*   top_ws  = (int*)(ws + off);   off += (size_t)BB * HH * NT * sizeof(int);
    float* mean_ws = (float*)(ws + off); off += (size_t)BB * HH * DD * sizeof(float);
    float* vpart_ws = (float*)(ws + off); off += (size_t)BB * HH * MVC * DD * sizeof(float);
    float* mpart_ws = (float*)(ws + off); off += (size_t)BB * HH * NCH * NT * sizeof(float);
    float* lpart_ws = (float*)(ws + off); off += (size_t)BB * HH * NCH * NT * sizeof(float);
    float* accpart_ws = (float*)(ws + off); off += (size_t)BB * HH * NCH * NT * DD * sizeof(float);
    float* base_ws = (float*)(ws + off); off += (size_t)BB * EE * sizeof(float);

    // K1: QKV projections (split-bf16 MFMA, 3 products)
    dim3 g1(EE / 128, (BB * LL) / 128, 3);
    proj_kernel<<<g1, 256, 0, stream>>>(query, key, value, Wq, Wk, Wv, bq, bk, bv,
                                        q_ws, k_ws, v_ws);
    // K2: mean of V (two-stage)
    meanv_part_kernel<<<BB * HH * MVC, 256, 0, stream>>>(v_ws, vpart_ws);
    meanv_comb_kernel<<<BB * HH, 64, 0, stream>>>(vpart_ws, mean_ws);
    // K3: sparsity measure (XCD-swizzled grid)
    measure_kernel<<<(LL / 4) * 32, 256, 0, stream>>>(q_ws, k_ws, idxs, M_ws);
    // K4: top-40 (single wave per bh)
    topk_kernel<<<BB * HH, 64, 0, stream>>>(M_ws, top_ws);
    // K5: split-K attention partials
    pv_kernel<<<BB * HH * NCH, 256, 0, stream>>>(q_ws, k_ws, v_ws, top_ws,
                                                 mpart_ws, lpart_ws, accpart_ws);
    // K6: output projection (base + broadcast + combine/correct)
    base_kernel<<<(BB * EE) / 4, 256, 0, stream>>>(mean_ws, Wo, bo, base_ws);
    bcast_kernel<<<(BB * LL * EE) / (256 * 4), 256, 0, stream>>>(base_ws, out);
    corr_kernel<<<BB * HH * NT, 256, 0, stream>>>(accpart_ws, lpart_ws, mpart_ws,
                                                  mean_ws, top_ws, Wo, out);
}